// Round 14
// baseline (115.313 us; speedup 1.0000x reference)
//
#include <hip/hip_runtime.h>
#include <cstddef>

// Hyperbolic supervised contrastive loss: fused MFMA bf16 Gram, symmetric wedge,
// double-buffered LDS reads, finalize fused into gram via done-counter.
// G ~= bf16(F) bf16(F)^T (validated r12/r13, absmax 0.0 vs threshold 9.4e-2).
// logits_max cancels (softmax shift invariance).
// 64-row x 128-col tiles, upper wedge bi <= 2bj+1 -> 1056 blocks (~4.1/CU).
// Pair (r,c), r<c in exactly one tile (r/64, c/128); mask row<col; contributes
// to row stats (reg acc -> shfl -> atomics) and col stats (shfl -> LDS slices
// -> atomics). B-tile 32 KB LDS, 16B-chunk XOR swizzle (c ^= row&7).
// bhA/bhB named-register double buffer: fj+1 ds_reads issue before fj MFMA+epi.
// Last gram block (device done-counter + threadfence) runs finalize inline:
// saves one graph node (~5us/node measured r5/r7/r12 cross-round).
// exp(logit) = ratio^20 via 5 mults; logit = 20*ln2*log2(ratio).

typedef __bf16 bf16x8 __attribute__((ext_vector_type(8)));
typedef __bf16 bf16x4 __attribute__((ext_vector_type(4)));
typedef float  f32x4  __attribute__((ext_vector_type(4)));

#define C_CONST 0.01f
#define RATIO_MIN 5.000025e-06f           // ratio at clamp 1-1e-5
#define LOGIT_SCALE 13.86294361119890619f // 20*ln(2)
#define TEMP 0.5f
#define LN2 0.69314718055994530942f
constexpr int DD = 128;

// bf16 convert + row squared-norms + zero stats + zero done-counter.
__global__ __launch_bounds__(256) void prep_kernel(
    const float* __restrict__ F, __bf16* __restrict__ Fh, float* __restrict__ sq,
    float* __restrict__ denom, float* __restrict__ possum, float* __restrict__ npos,
    unsigned int* __restrict__ cnt) {
  const int tid = threadIdx.x;
  const int lane = tid & 31;
  const int row = blockIdx.x * 8 + (tid >> 5);
  if (blockIdx.x == 0 && tid == 0) *cnt = 0u;
  const float4 v = *reinterpret_cast<const float4*>(F + (size_t)row * DD + lane * 4);
  float s = v.x * v.x + v.y * v.y + v.z * v.z + v.w * v.w;
  bf16x4 h;
  h[0] = (__bf16)v.x; h[1] = (__bf16)v.y; h[2] = (__bf16)v.z; h[3] = (__bf16)v.w;
  *reinterpret_cast<bf16x4*>(Fh + (size_t)row * DD + lane * 4) = h;
#pragma unroll
  for (int off = 1; off < 32; off <<= 1) s += __shfl_xor(s, off);
  if (lane == 0) { sq[row] = s; denom[row] = 0.f; possum[row] = 0.f; npos[row] = 0.f; }
}

// C/D layout (verified m89): value r of frag fj at
// row = row0 + lg*4 + r, col = col0 + fj*16 + ln.
__global__ __launch_bounds__(256, 4) void gram_kernel(
    const __bf16* __restrict__ Fh,
    const float* __restrict__ sq, const int* __restrict__ labels,
    float* __restrict__ denom, float* __restrict__ possum, float* __restrict__ npos,
    unsigned int* __restrict__ cnt, float* __restrict__ out,
    int B, int nblocks) {
  __shared__ __bf16 Bs[128 * 128];          // 32 KB B-tile, chunk-XOR swizzle
  __shared__ float colAcc[4][3][128];       // per-wave col-side slices (6 KB)
  char* BsB = reinterpret_cast<char*>(Bs);

  const int tid = threadIdx.x;
  const int l  = tid & 63;
  const int w  = tid >> 6;
  const int lg = l >> 4, ln = l & 15;
  const int lx = ln & 7;

  // wedge decode: block t -> (bi, bj), bi in [0, 2bj+2). S(bj) = bj^2 + bj.
  const int t = blockIdx.x;
  int bj = (int)((sqrtf((float)(4 * t + 1)) - 1.f) * 0.5f);
  while (bj * bj + bj > t) --bj;
  while ((bj + 1) * (bj + 1) + (bj + 1) <= t) ++bj;
  const int bi = t - (bj * bj + bj);

  const int row0 = bi * 64 + w * 16;
  const int col0 = bj * 128;

  // --- stage B tile into LDS: linear dest, source chunk pre-swizzled
#pragma unroll
  for (int j = 0; j < 8; ++j) {
    const int k = tid + j * 256;            // chunk id 0..2047
    const int row = k >> 4;
    const int cc = (k & 15) ^ (row & 7);
    bf16x8 v = *reinterpret_cast<const bf16x8*>(Fh + (size_t)(col0 + row) * DD + cc * 8);
    *reinterpret_cast<bf16x8*>(BsB + (size_t)k * 16) = v;
  }

  // --- A fragments to regs
  const __bf16* Ahp = Fh + (size_t)(row0 + ln) * DD + lg * 8;
  bf16x8 ah0 = *reinterpret_cast<const bf16x8*>(Ahp);
  bf16x8 ah1 = *reinterpret_cast<const bf16x8*>(Ahp + 32);
  bf16x8 ah2 = *reinterpret_cast<const bf16x8*>(Ahp + 64);
  bf16x8 ah3 = *reinterpret_cast<const bf16x8*>(Ahp + 96);

  // --- row/col metadata hoisted pre-barrier
  float si[4]; int li[4];
#pragma unroll
  for (int r = 0; r < 4; ++r) {
    const int row = row0 + lg * 4 + r;
    si[r] = sq[row];
    li[r] = labels[row];
  }
  float sqj[8]; int labj[8];
#pragma unroll
  for (int fj = 0; fj < 8; ++fj) {
    sqj[fj]  = sq[col0 + fj * 16 + ln];
    labj[fj] = labels[col0 + fj * 16 + ln];
  }

  // thread-invariant swizzled byte offsets for the 4 k-chunks
  const int o0 = ((0 * 4 + lg) ^ lx) << 4;
  const int o1 = ((1 * 4 + lg) ^ lx) << 4;
  const int o2 = ((2 * 4 + lg) ^ lx) << 4;
  const int o3 = ((3 * 4 + lg) ^ lx) << 4;

  __syncthreads();

  float dacc[4] = {}, pacc[4] = {}, nacc[4] = {};

#define LOADB(P0, P1, P2, P3, FJ) do {                                   \
    const int rb_ = ((FJ) * 16 + ln) * 256;                              \
    P0 = *reinterpret_cast<const bf16x8*>(BsB + rb_ + o0);               \
    P1 = *reinterpret_cast<const bf16x8*>(BsB + rb_ + o1);               \
    P2 = *reinterpret_cast<const bf16x8*>(BsB + rb_ + o2);               \
    P3 = *reinterpret_cast<const bf16x8*>(BsB + rb_ + o3);               \
  } while (0)

#define DO_FJ(FJ, C0, C1, C2, C3) do {                                   \
    f32x4 x_ = (f32x4){0.f, 0.f, 0.f, 0.f};                              \
    f32x4 y_ = (f32x4){0.f, 0.f, 0.f, 0.f};                              \
    x_ = __builtin_amdgcn_mfma_f32_16x16x32_bf16(ah0, C0, x_, 0, 0, 0);  \
    y_ = __builtin_amdgcn_mfma_f32_16x16x32_bf16(ah2, C2, y_, 0, 0, 0);  \
    x_ = __builtin_amdgcn_mfma_f32_16x16x32_bf16(ah1, C1, x_, 0, 0, 0);  \
    y_ = __builtin_amdgcn_mfma_f32_16x16x32_bf16(ah3, C3, y_, 0, 0, 0);  \
    const f32x4 acc_ = x_ + y_;                                          \
    const int col = col0 + (FJ) * 16 + ln;                               \
    const float sjv = sqj[FJ];                                           \
    const int   ljv = labj[FJ];                                          \
    const float qv = C_CONST * sjv;                                      \
    const float bb = 1.f - qv;                                           \
    const float b2 = bb * bb;                                            \
    float cd = 0.f, cp = 0.f, cn = 0.f;                                  \
    _Pragma("unroll")                                                    \
    for (int r = 0; r < 4; ++r) {                                        \
      const int row = row0 + lg * 4 + r;                                 \
      const float g   = acc_[r];                                         \
      const float pi_ = C_CONST * si[r];                                 \
      const float tt  = fmaf(-2.f * C_CONST, g, 1.f);                    \
      const float aa  = tt + pi_;                                        \
      const float den = fabsf(fmaf(pi_, qv, tt));                        \
      float ns = aa * aa * sjv;                                          \
      ns = fmaf(b2, si[r], ns);                                          \
      ns = fmaf(-2.f * aa * bb, g, ns);                                  \
      ns = fmaxf(ns, 0.f);                                               \
      const float rr = __builtin_amdgcn_sqrtf(C_CONST * ns);             \
      float ratio = (den - rr) * __builtin_amdgcn_rcpf(den + rr);        \
      ratio = fmaxf(ratio, RATIO_MIN);                                   \
      const float P = __builtin_amdgcn_logf(ratio);                      \
      const float t2_ = ratio * ratio;                                   \
      const float t4_ = t2_ * t2_;                                       \
      const float t5_ = t4_ * ratio;                                     \
      const float t10_ = t5_ * t5_;                                      \
      const float e = t10_ * t10_;                                       \
      const bool mask = row < col;                                       \
      const bool same = mask && (ljv == li[r]);                          \
      const float ev = mask ? e : 0.f;                                   \
      const float pv = same ? LOGIT_SCALE * P : 0.f;                     \
      const float nv = same ? 1.f : 0.f;                                 \
      dacc[r] += ev; pacc[r] += pv; nacc[r] += nv;                       \
      cd += ev; cp += pv; cn += nv;                                      \
    }                                                                    \
    cd += __shfl_xor(cd, 16); cd += __shfl_xor(cd, 32);                  \
    cp += __shfl_xor(cp, 16); cp += __shfl_xor(cp, 32);                  \
    cn += __shfl_xor(cn, 16); cn += __shfl_xor(cn, 32);                  \
    if (l < 16) {                                                        \
      colAcc[w][0][(FJ) * 16 + ln] = cd;                                 \
      colAcc[w][1][(FJ) * 16 + ln] = cp;                                 \
      colAcc[w][2][(FJ) * 16 + ln] = cn;                                 \
    }                                                                    \
  } while (0)

  bf16x8 a0_, a1_, a2_, a3_, b0_, b1_, b2_, b3_;
  LOADB(a0_, a1_, a2_, a3_, 0);
  LOADB(b0_, b1_, b2_, b3_, 1); DO_FJ(0, a0_, a1_, a2_, a3_);
  LOADB(a0_, a1_, a2_, a3_, 2); DO_FJ(1, b0_, b1_, b2_, b3_);
  LOADB(b0_, b1_, b2_, b3_, 3); DO_FJ(2, a0_, a1_, a2_, a3_);
  LOADB(a0_, a1_, a2_, a3_, 4); DO_FJ(3, b0_, b1_, b2_, b3_);
  LOADB(b0_, b1_, b2_, b3_, 5); DO_FJ(4, a0_, a1_, a2_, a3_);
  LOADB(a0_, a1_, a2_, a3_, 6); DO_FJ(5, b0_, b1_, b2_, b3_);
  LOADB(b0_, b1_, b2_, b3_, 7); DO_FJ(6, a0_, a1_, a2_, a3_);
  DO_FJ(7, b0_, b1_, b2_, b3_);

#undef LOADB
#undef DO_FJ

  // row-side: reduce over the 16 ln lanes; one atomic per row per stat
#pragma unroll
  for (int r = 0; r < 4; ++r) {
    float d = dacc[r], p = pacc[r], n = nacc[r];
#pragma unroll
    for (int off = 1; off < 16; off <<= 1) {
      d += __shfl_xor(d, off);
      p += __shfl_xor(p, off);
      n += __shfl_xor(n, off);
    }
    if (ln == 0) {
      const int row = row0 + lg * 4 + r;
      atomicAdd(&denom[row], d);
      atomicAdd(&possum[row], p);
      atomicAdd(&npos[row], n);
    }
  }

  // col-side: sum the 4 wave slices, one atomic per col per stat
  __syncthreads();
  if (tid < 128) {
    const float d = colAcc[0][0][tid] + colAcc[1][0][tid] + colAcc[2][0][tid] + colAcc[3][0][tid];
    const float p = colAcc[0][1][tid] + colAcc[1][1][tid] + colAcc[2][1][tid] + colAcc[3][1][tid];
    const float n = colAcc[0][2][tid] + colAcc[1][2][tid] + colAcc[2][2][tid] + colAcc[3][2][tid];
    atomicAdd(&denom[col0 + tid], d);
    atomicAdd(&possum[col0 + tid], p);
    atomicAdd(&npos[col0 + tid], n);
  }

  // --- fused finalize: last block to arrive does it (no residency assumption)
  __threadfence();
  __shared__ unsigned int lastFlag;
  if (tid == 0)
    lastFlag = (atomicAdd(cnt, 1u) == (unsigned)(nblocks - 1)) ? 1u : 0u;
  __syncthreads();
  if (lastFlag != 0u) {
    float s_loss = 0.f, s_valid = 0.f;
    for (int i = tid; i < B; i += 256) {
      const float n = __hip_atomic_load(&npos[i],  __ATOMIC_RELAXED, __HIP_MEMORY_SCOPE_AGENT);
      const float d = __hip_atomic_load(&denom[i], __ATOMIC_RELAXED, __HIP_MEMORY_SCOPE_AGENT);
      const float p = __hip_atomic_load(&possum[i],__ATOMIC_RELAXED, __HIP_MEMORY_SCOPE_AGENT);
      if (n > 0.f) {
        const float ln_d = __builtin_amdgcn_logf(d) * LN2;
        const float rl = -(p - n * ln_d) / n * TEMP;
        if (!(rl != rl)) s_loss += rl;   // NaN -> 0 like reference
        s_valid += 1.f;
      }
    }
#pragma unroll
    for (int off = 1; off < 64; off <<= 1) {
      s_loss += __shfl_xor(s_loss, off);
      s_valid += __shfl_xor(s_valid, off);
    }
    __shared__ float red[8];
    if ((tid & 63) == 0) { red[w] = s_loss; red[w + 4] = s_valid; }
    __syncthreads();
    if (tid == 0) {
      const float L = red[0] + red[1] + red[2] + red[3];
      const float V = red[4] + red[5] + red[6] + red[7];
      out[0] = L / fmaxf(V, 1.f);
    }
  }
}

extern "C" void kernel_launch(void* const* d_in, const int* in_sizes, int n_in,
                              void* d_out, int out_size, void* d_ws, size_t ws_size,
                              hipStream_t stream) {
  const float* F = (const float*)d_in[0];
  const int* labels = (const int*)d_in[1];
  const int B = in_sizes[1];           // 4096

  float* sq     = (float*)d_ws;
  float* denom  = sq + B;
  float* possum = denom + B;
  float* npos   = possum + B;
  unsigned int* cnt = (unsigned int*)(npos + B);
  __bf16* Fh = (__bf16*)(cnt + 64);    // 256B-aligned pad

  const int nbj = B / 128;             // 32
  const int nblocks = nbj * nbj + nbj; // sum over bj of (2bj+2) = 1056

  prep_kernel<<<dim3(B / 8), dim3(256), 0, stream>>>(F, Fh, sq, denom, possum, npos, cnt);
  gram_kernel<<<dim3(nblocks), dim3(256), 0, stream>>>(
      Fh, sq, labels, denom, possum, npos, cnt, (float*)d_out, B, nblocks);
}

// Round 15
// 59.644 us; speedup vs baseline: 1.9333x; 1.9333x over previous
//
#include <hip/hip_runtime.h>
#include <cstddef>

// Hyperbolic supervised contrastive loss, fused, MFMA bf16 Gram, symmetric.
// G ~= bf16(F) bf16(F)^T (validated r12-r14, absmax 0.0 vs threshold 9.4e-2).
// logits_max cancels (softmax shift invariance).
// r14 lesson (measured): per-block __threadfence() fused-finalize = device-scope
// L2 writeback x1056 -> WRITE_SIZE 35MB, gram 117us. Reverted to 3 kernels.
// This round: 64x64 tiles, triangular wedge bi<=bj (nt=64, 2080 blocks),
// LDS 19 KB (16 KB B-tile + 3 KB colAcc) + VGPR<=64 -> 8 blocks/CU, 32 waves/CU
// (r8-r13 ran at 4 blocks/CU; occupancy was the only lever that ever won).
// Pair (r,c) r<c lives in exactly one tile (r/64, c/64), bi<=bj automatic.
// Mask row<col; row stats: reg acc -> shfl(ln) -> atomics; col stats:
// shfl(lg) -> per-wave LDS slices -> atomics.
// B-tile 16B-chunk XOR swizzle (c ^= row&7), linear dest + pre-swizzled src.
// exp(logit) = ratio^20 via 5 mults; logit = 20*ln2*log2(ratio).

typedef __bf16 bf16x8 __attribute__((ext_vector_type(8)));
typedef __bf16 bf16x4 __attribute__((ext_vector_type(4)));
typedef float  f32x4  __attribute__((ext_vector_type(4)));

#define C_CONST 0.01f
#define RATIO_MIN 5.000025e-06f           // ratio at clamp 1-1e-5
#define LOGIT_SCALE 13.86294361119890619f // 20*ln(2)
#define TEMP 0.5f
#define LN2 0.69314718055994530942f
constexpr int DD = 128;

// bf16 convert + row squared-norms + zero stat arrays. 8 rows/block.
__global__ __launch_bounds__(256) void prep_kernel(
    const float* __restrict__ F, __bf16* __restrict__ Fh, float* __restrict__ sq,
    float* __restrict__ denom, float* __restrict__ possum, float* __restrict__ npos) {
  const int tid = threadIdx.x;
  const int lane = tid & 31;
  const int row = blockIdx.x * 8 + (tid >> 5);
  const float4 v = *reinterpret_cast<const float4*>(F + (size_t)row * DD + lane * 4);
  float s = v.x * v.x + v.y * v.y + v.z * v.z + v.w * v.w;
  bf16x4 h;
  h[0] = (__bf16)v.x; h[1] = (__bf16)v.y; h[2] = (__bf16)v.z; h[3] = (__bf16)v.w;
  *reinterpret_cast<bf16x4*>(Fh + (size_t)row * DD + lane * 4) = h;
#pragma unroll
  for (int off = 1; off < 32; off <<= 1) s += __shfl_xor(s, off);
  if (lane == 0) { sq[row] = s; denom[row] = 0.f; possum[row] = 0.f; npos[row] = 0.f; }
}

// 64x64 tile; 4 waves, wave w owns rows row0..row0+15 (1 row-frag x 4 col-frags).
// C/D layout (verified m89): value r of frag fj at
// row = row0 + lg*4 + r, col = col0 + fj*16 + ln.
__global__ __launch_bounds__(256, 8) void gram_kernel(
    const __bf16* __restrict__ Fh,
    const float* __restrict__ sq, const int* __restrict__ labels,
    float* __restrict__ denom, float* __restrict__ possum, float* __restrict__ npos,
    int B, int nt) {
  __shared__ __bf16 Bs[64 * 128];           // 16 KB B-tile, chunk-XOR swizzle
  __shared__ float colAcc[4][3][64];        // per-wave col-side slices (3 KB)
  char* BsB = reinterpret_cast<char*>(Bs);

  const int tid = threadIdx.x;
  const int l  = tid & 63;
  const int w  = tid >> 6;
  const int lg = l >> 4, ln = l & 15;
  const int lx = ln & 7;

  // triangular decode: block t -> (bi, bj), bi <= bj. S(bi) = bi*nt - bi(bi-1)/2
  const int t = blockIdx.x;
  int bi = (int)((2 * nt + 1 - sqrtf((float)((2 * nt + 1) * (2 * nt + 1) - 8 * t))) * 0.5f);
  while ((bi + 1) * nt - ((bi + 1) * bi) / 2 <= t) ++bi;
  while (bi * nt - (bi * (bi - 1)) / 2 > t) --bi;
  const int bj = bi + (t - (bi * nt - (bi * (bi - 1)) / 2));

  const int row0 = bi * 64 + w * 16;
  const int col0 = bj * 64;

  // --- stage B tile (64 rows x 128 dims) into LDS: linear dest, pre-swizzled src
  // LDS chunk k (16B) of row r holds global chunk ((k&15) ^ (r&7)) of row r.
#pragma unroll
  for (int j = 0; j < 4; ++j) {
    const int k = tid + j * 256;            // chunk id 0..1023
    const int row = k >> 4;
    const int cc = (k & 15) ^ (row & 7);
    bf16x8 v = *reinterpret_cast<const bf16x8*>(Fh + (size_t)(col0 + row) * DD + cc * 8);
    *reinterpret_cast<bf16x8*>(BsB + (size_t)k * 16) = v;
  }

  // --- A fragments to regs (16 VGPR)
  const __bf16* Ahp = Fh + (size_t)(row0 + ln) * DD + lg * 8;
  bf16x8 ah[4];
#pragma unroll
  for (int kt = 0; kt < 4; ++kt)
    ah[kt] = *reinterpret_cast<const bf16x8*>(Ahp + kt * 32);

  // --- row/col metadata hoisted pre-barrier
  float si[4]; int li[4];
#pragma unroll
  for (int r = 0; r < 4; ++r) {
    const int row = row0 + lg * 4 + r;
    si[r] = sq[row];
    li[r] = labels[row];
  }
  float sqj[4]; int labj[4];
#pragma unroll
  for (int fj = 0; fj < 4; ++fj) {
    sqj[fj]  = sq[col0 + fj * 16 + ln];
    labj[fj] = labels[col0 + fj * 16 + ln];
  }

  __syncthreads();

  float dacc[4] = {}, pacc[4] = {}, nacc[4] = {};

#pragma unroll
  for (int fj = 0; fj < 4; ++fj) {
    // 4 ds_read_b128 (swizzled)
    const int rbase = (fj * 16 + ln) * 256;
    bf16x8 bh[4];
#pragma unroll
    for (int kt = 0; kt < 4; ++kt)
      bh[kt] = *reinterpret_cast<const bf16x8*>(BsB + rbase + ((((kt * 4 + lg) ^ lx)) << 4));

    f32x4 acc = (f32x4){0.f, 0.f, 0.f, 0.f};
#pragma unroll
    for (int kt = 0; kt < 4; ++kt)
      acc = __builtin_amdgcn_mfma_f32_16x16x32_bf16(ah[kt], bh[kt], acc, 0, 0, 0);

    // fused epilogue for these 16 cols (all operands in regs)
    const int col = col0 + fj * 16 + ln;
    const float sjv = sqj[fj];
    const int   ljv = labj[fj];
    const float qv = C_CONST * sjv;
    const float b  = 1.f - qv;
    const float b2 = b * b;
    float cd = 0.f, cp = 0.f, cn = 0.f;
#pragma unroll
    for (int r = 0; r < 4; ++r) {
      const int row = row0 + lg * 4 + r;
      const float g   = acc[r];
      const float pi_ = C_CONST * si[r];
      const float tt  = fmaf(-2.f * C_CONST, g, 1.f);   // 1 - 2Cg
      const float a   = tt + pi_;                       // 1 - 2Cg + C si
      const float den = fabsf(fmaf(pi_, qv, tt));       // |1-2Cg+C^2 si sj|
      float ns = a * a * sjv;
      ns = fmaf(b2, si[r], ns);
      ns = fmaf(-2.f * a * b, g, ns);
      ns = fmaxf(ns, 0.f);
      const float rr = __builtin_amdgcn_sqrtf(C_CONST * ns);
      float ratio = (den - rr) * __builtin_amdgcn_rcpf(den + rr);
      ratio = fmaxf(ratio, RATIO_MIN);
      const float P = __builtin_amdgcn_logf(ratio);     // log2(ratio)
      const float t2 = ratio * ratio;                   // e = ratio^20
      const float t4 = t2 * t2;
      const float t5 = t4 * ratio;
      const float t10 = t5 * t5;
      const float e = t10 * t10;
      const bool mask = row < col;                      // strict upper: once/pair
      const bool same = mask && (ljv == li[r]);
      const float ev = mask ? e : 0.f;
      const float pv = same ? LOGIT_SCALE * P : 0.f;
      const float nv = same ? 1.f : 0.f;
      dacc[r] += ev; pacc[r] += pv; nacc[r] += nv;
      cd += ev; cp += pv; cn += nv;
    }
    // col-side: reduce over the 4 lg groups; per-wave LDS slice
    cd += __shfl_xor(cd, 16); cd += __shfl_xor(cd, 32);
    cp += __shfl_xor(cp, 16); cp += __shfl_xor(cp, 32);
    cn += __shfl_xor(cn, 16); cn += __shfl_xor(cn, 32);
    if (l < 16) {
      colAcc[w][0][fj * 16 + ln] = cd;
      colAcc[w][1][fj * 16 + ln] = cp;
      colAcc[w][2][fj * 16 + ln] = cn;
    }
  }

  // row-side: reduce over the 16 ln lanes; one atomic per row per stat
#pragma unroll
  for (int r = 0; r < 4; ++r) {
    float d = dacc[r], p = pacc[r], n = nacc[r];
#pragma unroll
    for (int off = 1; off < 16; off <<= 1) {
      d += __shfl_xor(d, off);
      p += __shfl_xor(p, off);
      n += __shfl_xor(n, off);
    }
    if (ln == 0) {
      const int row = row0 + lg * 4 + r;
      atomicAdd(&denom[row], d);
      atomicAdd(&possum[row], p);
      atomicAdd(&npos[row], n);
    }
  }

  // col-side: sum the 4 wave slices, one atomic per col per stat
  __syncthreads();
  if (tid < 64) {
    const float d = colAcc[0][0][tid] + colAcc[1][0][tid] + colAcc[2][0][tid] + colAcc[3][0][tid];
    const float p = colAcc[0][1][tid] + colAcc[1][1][tid] + colAcc[2][1][tid] + colAcc[3][1][tid];
    const float n = colAcc[0][2][tid] + colAcc[1][2][tid] + colAcc[2][2][tid] + colAcc[3][2][tid];
    atomicAdd(&denom[col0 + tid], d);
    atomicAdd(&possum[col0 + tid], p);
    atomicAdd(&npos[col0 + tid], n);
  }
}

// single finalize: 1 block x 1024 threads, reads only 48 KB (r12-proven ~4us)
__global__ __launch_bounds__(1024) void finalize_kernel(
    const float* __restrict__ denom, const float* __restrict__ possum,
    const float* __restrict__ npos, float* __restrict__ out, int B) {
  float s_loss = 0.f, s_valid = 0.f;
#pragma unroll
  for (int j = 0; j < 4; ++j) {
    const int i = threadIdx.x + j * 1024;
    const float n = npos[i];
    const float d = denom[i];
    const float p = possum[i];
    if (n > 0.f) {
      float ln_d = __builtin_amdgcn_logf(d) * LN2;
      float rl = -(p - n * ln_d) / n * TEMP;
      if (!(rl != rl)) s_loss += rl;   // NaN -> 0 like reference
      s_valid += 1.f;
    }
  }
#pragma unroll
  for (int off = 1; off < 64; off <<= 1) {
    s_loss += __shfl_xor(s_loss, off);
    s_valid += __shfl_xor(s_valid, off);
  }
  __shared__ float red[32];
  const int wid = threadIdx.x >> 6;
  if ((threadIdx.x & 63) == 0) { red[wid] = s_loss; red[wid + 16] = s_valid; }
  __syncthreads();
  if (threadIdx.x == 0) {
    float L = 0.f, V = 0.f;
#pragma unroll
    for (int i = 0; i < 16; ++i) { L += red[i]; V += red[i + 16]; }
    out[0] = L / fmaxf(V, 1.f);
  }
}

extern "C" void kernel_launch(void* const* d_in, const int* in_sizes, int n_in,
                              void* d_out, int out_size, void* d_ws, size_t ws_size,
                              hipStream_t stream) {
  const float* F = (const float*)d_in[0];
  const int* labels = (const int*)d_in[1];
  const int B = in_sizes[1];           // 4096

  float* sq     = (float*)d_ws;
  float* denom  = sq + B;
  float* possum = denom + B;
  float* npos   = possum + B;
  __bf16* Fh = (__bf16*)(npos + B);

  const int nt = B / 64;               // 64
  const int nblocks = nt * (nt + 1) / 2; // 2080

  prep_kernel<<<dim3(B / 8), dim3(256), 0, stream>>>(F, Fh, sq, denom, possum, npos);
  gram_kernel<<<dim3(nblocks), dim3(256), 0, stream>>>(
      Fh, sq, labels, denom, possum, npos, B, nt);
  finalize_kernel<<<1, dim3(1024), 0, stream>>>(denom, possum, npos, (float*)d_out, B);
}

// Round 16
// 55.801 us; speedup vs baseline: 2.0665x; 1.0689x over previous
//
#include <hip/hip_runtime.h>
#include <cstddef>

// Hyperbolic supervised contrastive loss, fused, MFMA bf16 Gram, symmetric.
// G ~= bf16(F) bf16(F)^T (validated r12-r15, absmax 0.0 vs threshold 9.4e-2).
// logits_max cancels (softmax shift invariance).
// r15 lesson (measured): 800K device-scope atomicAdds -> 54 MB of coherence
// line-fetches (FETCH_SIZE) at 1.1 TB/s = the whole 50us gram duration.
// NO GLOBAL ATOMICS: wedge gives every (split, row) partial a unique writer:
//   entry (s, r), br=r/64:  br<s -> block (br,s) row-side
//                           br>s -> block (s,br) col-side
//                           br==s -> diagonal block stores row+col sum
// -> plain coalesced 64-float stores, no zero-init, no RMW.
// 64x64 tiles, triangular wedge bi<=bj (nt=64, 2080 blocks), LDS ~20 KB,
// launch_bounds(256,8) -> 8 blocks/CU, 32 waves/CU (r15-proven residency).
// B-tile 16B-chunk XOR swizzle (c ^= row&7), linear dest + pre-swizzled src.
// exp(logit) = ratio^20 via 5 mults; logit = 20*ln2*log2(ratio).

typedef __bf16 bf16x8 __attribute__((ext_vector_type(8)));
typedef __bf16 bf16x4 __attribute__((ext_vector_type(4)));
typedef float  f32x4  __attribute__((ext_vector_type(4)));

#define C_CONST 0.01f
#define RATIO_MIN 5.000025e-06f           // ratio at clamp 1-1e-5
#define LOGIT_SCALE 13.86294361119890619f // 20*ln(2)
#define TEMP 0.5f
#define LN2 0.69314718055994530942f
constexpr int DD = 128;
constexpr int NSPLIT = 64;                // = nt
constexpr int FBLK = 16;

// bf16 convert + row squared-norms. 8 rows/block. (No stat zeroing needed.)
__global__ __launch_bounds__(256) void prep_kernel(
    const float* __restrict__ F, __bf16* __restrict__ Fh, float* __restrict__ sq) {
  const int tid = threadIdx.x;
  const int lane = tid & 31;
  const int row = blockIdx.x * 8 + (tid >> 5);
  const float4 v = *reinterpret_cast<const float4*>(F + (size_t)row * DD + lane * 4);
  float s = v.x * v.x + v.y * v.y + v.z * v.z + v.w * v.w;
  bf16x4 h;
  h[0] = (__bf16)v.x; h[1] = (__bf16)v.y; h[2] = (__bf16)v.z; h[3] = (__bf16)v.w;
  *reinterpret_cast<bf16x4*>(Fh + (size_t)row * DD + lane * 4) = h;
#pragma unroll
  for (int off = 1; off < 32; off <<= 1) s += __shfl_xor(s, off);
  if (lane == 0) sq[row] = s;
}

// 64x64 tile; 4 waves, wave w owns rows row0..row0+15 (1 row-frag x 4 col-frags).
// C/D layout (verified m89): value r of frag fj at
// row = row0 + lg*4 + r, col = col0 + fj*16 + ln.
__global__ __launch_bounds__(256, 8) void gram_kernel(
    const __bf16* __restrict__ Fh,
    const float* __restrict__ sq, const int* __restrict__ labels,
    float* __restrict__ dpart, float* __restrict__ ppart, float* __restrict__ npart,
    int B, int nt) {
  __shared__ __bf16 Bs[64 * 128];           // 16 KB B-tile, chunk-XOR swizzle
  __shared__ float colAcc[4][3][64];        // per-wave col-side slices (3 KB)
  __shared__ float rowAcc[4][3][16];        // per-wave row-side slices (768 B)
  char* BsB = reinterpret_cast<char*>(Bs);

  const int tid = threadIdx.x;
  const int l  = tid & 63;
  const int w  = tid >> 6;
  const int lg = l >> 4, ln = l & 15;
  const int lx = ln & 7;

  // triangular decode: block t -> (bi, bj), bi <= bj. S(bi) = bi*nt - bi(bi-1)/2
  const int t = blockIdx.x;
  int bi = (int)((2 * nt + 1 - sqrtf((float)((2 * nt + 1) * (2 * nt + 1) - 8 * t))) * 0.5f);
  while ((bi + 1) * nt - ((bi + 1) * bi) / 2 <= t) ++bi;
  while (bi * nt - (bi * (bi - 1)) / 2 > t) --bi;
  const int bj = bi + (t - (bi * nt - (bi * (bi - 1)) / 2));

  const int row0 = bi * 64 + w * 16;
  const int col0 = bj * 64;

  // --- stage B tile (64 rows x 128 dims) into LDS: linear dest, pre-swizzled src
  // LDS chunk k (16B) of row r holds global chunk ((k&15) ^ (r&7)) of row r.
#pragma unroll
  for (int j = 0; j < 4; ++j) {
    const int k = tid + j * 256;            // chunk id 0..1023
    const int row = k >> 4;
    const int cc = (k & 15) ^ (row & 7);
    bf16x8 v = *reinterpret_cast<const bf16x8*>(Fh + (size_t)(col0 + row) * DD + cc * 8);
    *reinterpret_cast<bf16x8*>(BsB + (size_t)k * 16) = v;
  }

  // --- A fragments to regs (16 VGPR)
  const __bf16* Ahp = Fh + (size_t)(row0 + ln) * DD + lg * 8;
  bf16x8 ah[4];
#pragma unroll
  for (int kt = 0; kt < 4; ++kt)
    ah[kt] = *reinterpret_cast<const bf16x8*>(Ahp + kt * 32);

  // --- row/col metadata hoisted pre-barrier
  float si[4]; int li[4];
#pragma unroll
  for (int r = 0; r < 4; ++r) {
    const int row = row0 + lg * 4 + r;
    si[r] = sq[row];
    li[r] = labels[row];
  }
  float sqj[4]; int labj[4];
#pragma unroll
  for (int fj = 0; fj < 4; ++fj) {
    sqj[fj]  = sq[col0 + fj * 16 + ln];
    labj[fj] = labels[col0 + fj * 16 + ln];
  }

  __syncthreads();

  float dacc[4] = {}, pacc[4] = {}, nacc[4] = {};

#pragma unroll
  for (int fj = 0; fj < 4; ++fj) {
    // 4 ds_read_b128 (swizzled)
    const int rbase = (fj * 16 + ln) * 256;
    bf16x8 bh[4];
#pragma unroll
    for (int kt = 0; kt < 4; ++kt)
      bh[kt] = *reinterpret_cast<const bf16x8*>(BsB + rbase + ((((kt * 4 + lg) ^ lx)) << 4));

    f32x4 acc = (f32x4){0.f, 0.f, 0.f, 0.f};
#pragma unroll
    for (int kt = 0; kt < 4; ++kt)
      acc = __builtin_amdgcn_mfma_f32_16x16x32_bf16(ah[kt], bh[kt], acc, 0, 0, 0);

    // fused epilogue for these 16 cols (all operands in regs)
    const int col = col0 + fj * 16 + ln;
    const float sjv = sqj[fj];
    const int   ljv = labj[fj];
    const float qv = C_CONST * sjv;
    const float b  = 1.f - qv;
    const float b2 = b * b;
    float cd = 0.f, cp = 0.f, cn = 0.f;
#pragma unroll
    for (int r = 0; r < 4; ++r) {
      const int row = row0 + lg * 4 + r;
      const float g   = acc[r];
      const float pi_ = C_CONST * si[r];
      const float tt  = fmaf(-2.f * C_CONST, g, 1.f);   // 1 - 2Cg
      const float a   = tt + pi_;                       // 1 - 2Cg + C si
      const float den = fabsf(fmaf(pi_, qv, tt));       // |1-2Cg+C^2 si sj|
      float ns = a * a * sjv;
      ns = fmaf(b2, si[r], ns);
      ns = fmaf(-2.f * a * b, g, ns);
      ns = fmaxf(ns, 0.f);
      const float rr = __builtin_amdgcn_sqrtf(C_CONST * ns);
      float ratio = (den - rr) * __builtin_amdgcn_rcpf(den + rr);
      ratio = fmaxf(ratio, RATIO_MIN);
      const float P = __builtin_amdgcn_logf(ratio);     // log2(ratio)
      const float t2 = ratio * ratio;                   // e = ratio^20
      const float t4 = t2 * t2;
      const float t5 = t4 * ratio;
      const float t10 = t5 * t5;
      const float e = t10 * t10;
      const bool mask = row < col;                      // strict upper: once/pair
      const bool same = mask && (ljv == li[r]);
      const float ev = mask ? e : 0.f;
      const float pv = same ? LOGIT_SCALE * P : 0.f;
      const float nv = same ? 1.f : 0.f;
      dacc[r] += ev; pacc[r] += pv; nacc[r] += nv;
      cd += ev; cp += pv; cn += nv;
    }
    // col-side: reduce over the 4 lg groups; per-wave LDS slice
    cd += __shfl_xor(cd, 16); cd += __shfl_xor(cd, 32);
    cp += __shfl_xor(cp, 16); cp += __shfl_xor(cp, 32);
    cn += __shfl_xor(cn, 16); cn += __shfl_xor(cn, 32);
    if (l < 16) {
      colAcc[w][0][fj * 16 + ln] = cd;
      colAcc[w][1][fj * 16 + ln] = cp;
      colAcc[w][2][fj * 16 + ln] = cn;
    }
  }

  // row-side: reduce over the 16 ln lanes -> per-wave LDS slice
#pragma unroll
  for (int r = 0; r < 4; ++r) {
    float d = dacc[r], p = pacc[r], n = nacc[r];
#pragma unroll
    for (int off = 1; off < 16; off <<= 1) {
      d += __shfl_xor(d, off);
      p += __shfl_xor(p, off);
      n += __shfl_xor(n, off);
    }
    if (ln == 0) {
      rowAcc[w][0][lg * 4 + r] = d;
      rowAcc[w][1][lg * 4 + r] = p;
      rowAcc[w][2][lg * 4 + r] = n;
    }
  }

  __syncthreads();

  // unique-writer coalesced partial stores (no atomics, no init needed):
  //   off-diag: split bj gets row-block bi (row-side); split bi gets
  //             row-block bj (col-side).  diag: one combined store.
  if (tid < 64) {
    const float rv0 = rowAcc[tid >> 4][0][tid & 15];
    const float rv1 = rowAcc[tid >> 4][1][tid & 15];
    const float rv2 = rowAcc[tid >> 4][2][tid & 15];
    const float cv0 = colAcc[0][0][tid] + colAcc[1][0][tid] + colAcc[2][0][tid] + colAcc[3][0][tid];
    const float cv1 = colAcc[0][1][tid] + colAcc[1][1][tid] + colAcc[2][1][tid] + colAcc[3][1][tid];
    const float cv2 = colAcc[0][2][tid] + colAcc[1][2][tid] + colAcc[2][2][tid] + colAcc[3][2][tid];
    if (bi == bj) {
      const size_t idx = (size_t)bi * B + bi * 64 + tid;
      dpart[idx] = rv0 + cv0;
      ppart[idx] = rv1 + cv1;
      npart[idx] = rv2 + cv2;
    } else {
      const size_t ridx = (size_t)bj * B + bi * 64 + tid;   // row-side
      dpart[ridx] = rv0; ppart[ridx] = rv1; npart[ridx] = rv2;
      const size_t cidx = (size_t)bi * B + bj * 64 + tid;   // col-side
      dpart[cidx] = cv0; ppart[cidx] = cv1; npart[cidx] = cv2;
    }
  }
}

// stage 1: one row per thread, 16 blocks of 256; per-block scalar partials
__global__ __launch_bounds__(256) void finalize_part(
    const float* __restrict__ dpart, const float* __restrict__ ppart,
    const float* __restrict__ npart, float* __restrict__ lossP,
    float* __restrict__ validP, int B) {
  const int i = blockIdx.x * 256 + threadIdx.x;
  float d = 0.f, p = 0.f, n = 0.f;
#pragma unroll 8
  for (int s = 0; s < NSPLIT; ++s) {
    d += dpart[(size_t)s * B + i];     // coalesced across threads
    p += ppart[(size_t)s * B + i];
    n += npart[(size_t)s * B + i];
  }
  float s_loss = 0.f, s_valid = 0.f;
  if (n > 0.f) {
    float ln_d = __builtin_amdgcn_logf(d) * LN2;
    float rl = -(p - n * ln_d) / n * TEMP;
    if (!(rl != rl)) s_loss = rl;      // NaN -> 0 like reference
    s_valid = 1.f;
  }
#pragma unroll
  for (int off = 1; off < 64; off <<= 1) {
    s_loss += __shfl_xor(s_loss, off);
    s_valid += __shfl_xor(s_valid, off);
  }
  __shared__ float red[8];
  const int wid = threadIdx.x >> 6;
  if ((threadIdx.x & 63) == 0) { red[wid] = s_loss; red[wid + 4] = s_valid; }
  __syncthreads();
  if (threadIdx.x == 0) {
    lossP[blockIdx.x]  = red[0] + red[1] + red[2] + red[3];
    validP[blockIdx.x] = red[4] + red[5] + red[6] + red[7];
  }
}

// stage 2: tiny final reduce
__global__ void finalize_final(const float* __restrict__ lossP,
                               const float* __restrict__ validP,
                               float* __restrict__ out) {
  const int t = threadIdx.x;
  float L = (t < FBLK) ? lossP[t] : 0.f;
  float V = (t < FBLK) ? validP[t] : 0.f;
#pragma unroll
  for (int off = 1; off < 64; off <<= 1) {
    L += __shfl_xor(L, off);
    V += __shfl_xor(V, off);
  }
  if (t == 0) out[0] = L / fmaxf(V, 1.f);
}

extern "C" void kernel_launch(void* const* d_in, const int* in_sizes, int n_in,
                              void* d_out, int out_size, void* d_ws, size_t ws_size,
                              hipStream_t stream) {
  const float* F = (const float*)d_in[0];
  const int* labels = (const int*)d_in[1];
  const int B = in_sizes[1];           // 4096

  float* sq    = (float*)d_ws;
  float* dpart = sq + B;
  float* ppart = dpart + (size_t)NSPLIT * B;
  float* npart = ppart + (size_t)NSPLIT * B;
  float* lossP = npart + (size_t)NSPLIT * B;
  float* validP = lossP + FBLK;
  __bf16* Fh = (__bf16*)(validP + FBLK);

  const int nt = B / 64;                 // 64
  const int nblocks = nt * (nt + 1) / 2; // 2080

  prep_kernel<<<dim3(B / 8), dim3(256), 0, stream>>>(F, Fh, sq);
  gram_kernel<<<dim3(nblocks), dim3(256), 0, stream>>>(
      Fh, sq, labels, dpart, ppart, npart, B, nt);
  finalize_part<<<dim3(FBLK), dim3(256), 0, stream>>>(
      dpart, ppart, npart, lossP, validP, B);
  finalize_final<<<1, dim3(64), 0, stream>>>(lossP, validP, (float*)d_out);
}

// Round 17
// 34.588 us; speedup vs baseline: 3.3339x; 1.6133x over previous
//
#include <hip/hip_runtime.h>
#include <cstddef>

// Hyperbolic supervised contrastive loss, fused, MFMA bf16 Gram, symmetric.
// G ~= bf16(F) bf16(F)^T (validated r12-r16, absmax 0.0 vs threshold 9.4e-2).
// logits_max cancels (softmax shift invariance).
// r16 lesson (measured): __launch_bounds__(256,8) = 64-VGPR cap -> VGPR_Count
// 32 + ~143 MB/dispatch scratch traffic (FETCH 58 + WRITE 85 MB) = the whole
// 47us. (256,4) = 128-VGPR cap: r12/r13 compiled this body spill-free.
// NO GLOBAL ATOMICS: wedge gives every (split, row) partial a unique writer:
//   entry (s, r), br=r/64:  br<s -> block (br,s) row-side
//                           br>s -> block (s,br) col-side
//                           br==s -> diagonal block stores row+col sum
// -> plain coalesced 64-float stores, no zero-init, no RMW.
// 64x64 tiles, triangular wedge bi<=bj (nt=64, 2080 blocks), LDS ~20 KB.
// B-tile 16B-chunk XOR swizzle (c ^= row&7), linear dest + pre-swizzled src.
// exp(logit) = ratio^20 via 5 mults; logit = 20*ln2*log2(ratio).

typedef __bf16 bf16x8 __attribute__((ext_vector_type(8)));
typedef __bf16 bf16x4 __attribute__((ext_vector_type(4)));
typedef float  f32x4  __attribute__((ext_vector_type(4)));

#define C_CONST 0.01f
#define RATIO_MIN 5.000025e-06f           // ratio at clamp 1-1e-5
#define LOGIT_SCALE 13.86294361119890619f // 20*ln(2)
#define TEMP 0.5f
#define LN2 0.69314718055994530942f
constexpr int DD = 128;
constexpr int NSPLIT = 64;                // = nt
constexpr int FBLK = 16;

// bf16 convert + row squared-norms. 8 rows/block.
__global__ __launch_bounds__(256) void prep_kernel(
    const float* __restrict__ F, __bf16* __restrict__ Fh, float* __restrict__ sq) {
  const int tid = threadIdx.x;
  const int lane = tid & 31;
  const int row = blockIdx.x * 8 + (tid >> 5);
  const float4 v = *reinterpret_cast<const float4*>(F + (size_t)row * DD + lane * 4);
  float s = v.x * v.x + v.y * v.y + v.z * v.z + v.w * v.w;
  bf16x4 h;
  h[0] = (__bf16)v.x; h[1] = (__bf16)v.y; h[2] = (__bf16)v.z; h[3] = (__bf16)v.w;
  *reinterpret_cast<bf16x4*>(Fh + (size_t)row * DD + lane * 4) = h;
#pragma unroll
  for (int off = 1; off < 32; off <<= 1) s += __shfl_xor(s, off);
  if (lane == 0) sq[row] = s;
}

// 64x64 tile; 4 waves, wave w owns rows row0..row0+15 (1 row-frag x 4 col-frags).
// C/D layout (verified m89): value r of frag fj at
// row = row0 + lg*4 + r, col = col0 + fj*16 + ln.
__global__ __launch_bounds__(256, 4) void gram_kernel(
    const __bf16* __restrict__ Fh,
    const float* __restrict__ sq, const int* __restrict__ labels,
    float* __restrict__ dpart, float* __restrict__ ppart, float* __restrict__ npart,
    int B, int nt) {
  __shared__ __bf16 Bs[64 * 128];           // 16 KB B-tile, chunk-XOR swizzle
  __shared__ float colAcc[4][3][64];        // per-wave col-side slices (3 KB)
  __shared__ float rowAcc[4][3][16];        // per-wave row-side slices (768 B)
  char* BsB = reinterpret_cast<char*>(Bs);

  const int tid = threadIdx.x;
  const int l  = tid & 63;
  const int w  = tid >> 6;
  const int lg = l >> 4, ln = l & 15;
  const int lx = ln & 7;

  // triangular decode: block t -> (bi, bj), bi <= bj. S(bi) = bi*nt - bi(bi-1)/2
  const int t = blockIdx.x;
  int bi = (int)((2 * nt + 1 - sqrtf((float)((2 * nt + 1) * (2 * nt + 1) - 8 * t))) * 0.5f);
  while ((bi + 1) * nt - ((bi + 1) * bi) / 2 <= t) ++bi;
  while (bi * nt - (bi * (bi - 1)) / 2 > t) --bi;
  const int bj = bi + (t - (bi * nt - (bi * (bi - 1)) / 2));

  const int row0 = bi * 64 + w * 16;
  const int col0 = bj * 64;

  // --- stage B tile (64 rows x 128 dims) into LDS: linear dest, pre-swizzled src
  // LDS chunk k (16B) of row r holds global chunk ((k&15) ^ (r&7)) of row r.
#pragma unroll
  for (int j = 0; j < 4; ++j) {
    const int k = tid + j * 256;            // chunk id 0..1023
    const int row = k >> 4;
    const int cc = (k & 15) ^ (row & 7);
    bf16x8 v = *reinterpret_cast<const bf16x8*>(Fh + (size_t)(col0 + row) * DD + cc * 8);
    *reinterpret_cast<bf16x8*>(BsB + (size_t)k * 16) = v;
  }

  // --- A fragments to regs (16 VGPR)
  const __bf16* Ahp = Fh + (size_t)(row0 + ln) * DD + lg * 8;
  bf16x8 ah[4];
#pragma unroll
  for (int kt = 0; kt < 4; ++kt)
    ah[kt] = *reinterpret_cast<const bf16x8*>(Ahp + kt * 32);

  // --- row/col metadata hoisted pre-barrier
  float si[4]; int li[4];
#pragma unroll
  for (int r = 0; r < 4; ++r) {
    const int row = row0 + lg * 4 + r;
    si[r] = sq[row];
    li[r] = labels[row];
  }
  float sqj[4]; int labj[4];
#pragma unroll
  for (int fj = 0; fj < 4; ++fj) {
    sqj[fj]  = sq[col0 + fj * 16 + ln];
    labj[fj] = labels[col0 + fj * 16 + ln];
  }

  __syncthreads();

  float dacc[4] = {}, pacc[4] = {}, nacc[4] = {};

#pragma unroll
  for (int fj = 0; fj < 4; ++fj) {
    // 4 ds_read_b128 (swizzled)
    const int rbase = (fj * 16 + ln) * 256;
    bf16x8 bh[4];
#pragma unroll
    for (int kt = 0; kt < 4; ++kt)
      bh[kt] = *reinterpret_cast<const bf16x8*>(BsB + rbase + ((((kt * 4 + lg) ^ lx)) << 4));

    f32x4 acc = (f32x4){0.f, 0.f, 0.f, 0.f};
#pragma unroll
    for (int kt = 0; kt < 4; ++kt)
      acc = __builtin_amdgcn_mfma_f32_16x16x32_bf16(ah[kt], bh[kt], acc, 0, 0, 0);

    // fused epilogue for these 16 cols (all operands in regs)
    const int col = col0 + fj * 16 + ln;
    const float sjv = sqj[fj];
    const int   ljv = labj[fj];
    const float qv = C_CONST * sjv;
    const float b  = 1.f - qv;
    const float b2 = b * b;
    float cd = 0.f, cp = 0.f, cn = 0.f;
#pragma unroll
    for (int r = 0; r < 4; ++r) {
      const int row = row0 + lg * 4 + r;
      const float g   = acc[r];
      const float pi_ = C_CONST * si[r];
      const float tt  = fmaf(-2.f * C_CONST, g, 1.f);   // 1 - 2Cg
      const float a   = tt + pi_;                       // 1 - 2Cg + C si
      const float den = fabsf(fmaf(pi_, qv, tt));       // |1-2Cg+C^2 si sj|
      float ns = a * a * sjv;
      ns = fmaf(b2, si[r], ns);
      ns = fmaf(-2.f * a * b, g, ns);
      ns = fmaxf(ns, 0.f);
      const float rr = __builtin_amdgcn_sqrtf(C_CONST * ns);
      float ratio = (den - rr) * __builtin_amdgcn_rcpf(den + rr);
      ratio = fmaxf(ratio, RATIO_MIN);
      const float P = __builtin_amdgcn_logf(ratio);     // log2(ratio)
      const float t2 = ratio * ratio;                   // e = ratio^20
      const float t4 = t2 * t2;
      const float t5 = t4 * ratio;
      const float t10 = t5 * t5;
      const float e = t10 * t10;
      const bool mask = row < col;                      // strict upper: once/pair
      const bool same = mask && (ljv == li[r]);
      const float ev = mask ? e : 0.f;
      const float pv = same ? LOGIT_SCALE * P : 0.f;
      const float nv = same ? 1.f : 0.f;
      dacc[r] += ev; pacc[r] += pv; nacc[r] += nv;
      cd += ev; cp += pv; cn += nv;
    }
    // col-side: reduce over the 4 lg groups; per-wave LDS slice
    cd += __shfl_xor(cd, 16); cd += __shfl_xor(cd, 32);
    cp += __shfl_xor(cp, 16); cp += __shfl_xor(cp, 32);
    cn += __shfl_xor(cn, 16); cn += __shfl_xor(cn, 32);
    if (l < 16) {
      colAcc[w][0][fj * 16 + ln] = cd;
      colAcc[w][1][fj * 16 + ln] = cp;
      colAcc[w][2][fj * 16 + ln] = cn;
    }
  }

  // row-side: reduce over the 16 ln lanes -> per-wave LDS slice
#pragma unroll
  for (int r = 0; r < 4; ++r) {
    float d = dacc[r], p = pacc[r], n = nacc[r];
#pragma unroll
    for (int off = 1; off < 16; off <<= 1) {
      d += __shfl_xor(d, off);
      p += __shfl_xor(p, off);
      n += __shfl_xor(n, off);
    }
    if (ln == 0) {
      rowAcc[w][0][lg * 4 + r] = d;
      rowAcc[w][1][lg * 4 + r] = p;
      rowAcc[w][2][lg * 4 + r] = n;
    }
  }

  __syncthreads();

  // unique-writer coalesced partial stores (no atomics, no init needed):
  //   off-diag: split bj gets row-block bi (row-side); split bi gets
  //             row-block bj (col-side).  diag: one combined store.
  if (tid < 64) {
    const float rv0 = rowAcc[tid >> 4][0][tid & 15];
    const float rv1 = rowAcc[tid >> 4][1][tid & 15];
    const float rv2 = rowAcc[tid >> 4][2][tid & 15];
    const float cv0 = colAcc[0][0][tid] + colAcc[1][0][tid] + colAcc[2][0][tid] + colAcc[3][0][tid];
    const float cv1 = colAcc[0][1][tid] + colAcc[1][1][tid] + colAcc[2][1][tid] + colAcc[3][1][tid];
    const float cv2 = colAcc[0][2][tid] + colAcc[1][2][tid] + colAcc[2][2][tid] + colAcc[3][2][tid];
    if (bi == bj) {
      const size_t idx = (size_t)bi * B + bi * 64 + tid;
      dpart[idx] = rv0 + cv0;
      ppart[idx] = rv1 + cv1;
      npart[idx] = rv2 + cv2;
    } else {
      const size_t ridx = (size_t)bj * B + bi * 64 + tid;   // row-side
      dpart[ridx] = rv0; ppart[ridx] = rv1; npart[ridx] = rv2;
      const size_t cidx = (size_t)bi * B + bj * 64 + tid;   // col-side
      dpart[cidx] = cv0; ppart[cidx] = cv1; npart[cidx] = cv2;
    }
  }
}

// stage 1: one row per thread, 16 blocks of 256; per-block scalar partials
__global__ __launch_bounds__(256) void finalize_part(
    const float* __restrict__ dpart, const float* __restrict__ ppart,
    const float* __restrict__ npart, float* __restrict__ lossP,
    float* __restrict__ validP, int B) {
  const int i = blockIdx.x * 256 + threadIdx.x;
  float d = 0.f, p = 0.f, n = 0.f;
#pragma unroll 8
  for (int s = 0; s < NSPLIT; ++s) {
    d += dpart[(size_t)s * B + i];     // coalesced across threads
    p += ppart[(size_t)s * B + i];
    n += npart[(size_t)s * B + i];
  }
  float s_loss = 0.f, s_valid = 0.f;
  if (n > 0.f) {
    float ln_d = __builtin_amdgcn_logf(d) * LN2;
    float rl = -(p - n * ln_d) / n * TEMP;
    if (!(rl != rl)) s_loss = rl;      // NaN -> 0 like reference
    s_valid = 1.f;
  }
#pragma unroll
  for (int off = 1; off < 64; off <<= 1) {
    s_loss += __shfl_xor(s_loss, off);
    s_valid += __shfl_xor(s_valid, off);
  }
  __shared__ float red[8];
  const int wid = threadIdx.x >> 6;
  if ((threadIdx.x & 63) == 0) { red[wid] = s_loss; red[wid + 4] = s_valid; }
  __syncthreads();
  if (threadIdx.x == 0) {
    lossP[blockIdx.x]  = red[0] + red[1] + red[2] + red[3];
    validP[blockIdx.x] = red[4] + red[5] + red[6] + red[7];
  }
}

// stage 2: tiny final reduce
__global__ void finalize_final(const float* __restrict__ lossP,
                               const float* __restrict__ validP,
                               float* __restrict__ out) {
  const int t = threadIdx.x;
  float L = (t < FBLK) ? lossP[t] : 0.f;
  float V = (t < FBLK) ? validP[t] : 0.f;
#pragma unroll
  for (int off = 1; off < 64; off <<= 1) {
    L += __shfl_xor(L, off);
    V += __shfl_xor(V, off);
  }
  if (t == 0) out[0] = L / fmaxf(V, 1.f);
}

extern "C" void kernel_launch(void* const* d_in, const int* in_sizes, int n_in,
                              void* d_out, int out_size, void* d_ws, size_t ws_size,
                              hipStream_t stream) {
  const float* F = (const float*)d_in[0];
  const int* labels = (const int*)d_in[1];
  const int B = in_sizes[1];           // 4096

  float* sq    = (float*)d_ws;
  float* dpart = sq + B;
  float* ppart = dpart + (size_t)NSPLIT * B;
  float* npart = ppart + (size_t)NSPLIT * B;
  float* lossP = npart + (size_t)NSPLIT * B;
  float* validP = lossP + FBLK;
  __bf16* Fh = (__bf16*)(validP + FBLK);

  const int nt = B / 64;                 // 64
  const int nblocks = nt * (nt + 1) / 2; // 2080

  prep_kernel<<<dim3(B / 8), dim3(256), 0, stream>>>(F, Fh, sq);
  gram_kernel<<<dim3(nblocks), dim3(256), 0, stream>>>(
      Fh, sq, labels, dpart, ppart, npart, B, nt);
  finalize_part<<<dim3(FBLK), dim3(256), 0, stream>>>(
      dpart, ppart, npart, lossP, validP, B);
  finalize_final<<<1, dim3(64), 0, stream>>>(lossP, validP, (float*)d_out);
}